// Round 1
// baseline (508.651 us; speedup 1.0000x reference)
//
#include <hip/hip_runtime.h>
#include <math.h>

namespace {

constexpr int Bn = 8, Rn = 96, Cn = 64, CINn = 8, COUTn = 64, KW = 8, CTn = 4;
constexpr int NO2 = 2 * COUTn;     // 128 gate channels
constexpr int TBC = 8;             // (b,c) pairs per block
constexpr int RC  = 12;            // rows per chunk
constexpr int NCHUNK = Rn / RC;    // 8

__global__ __launch_bounds__(256, 2)
void fused_tb2d(const float* __restrict__ x,   const float* __restrict__ xm,
                const float* __restrict__ Wd,  const float* __restrict__ bd,
                const float* __restrict__ Wm,  const float* __restrict__ bm,
                const float* __restrict__ Gd,  const float* __restrict__ bgd,
                const float* __restrict__ Gm,  const float* __restrict__ bgm,
                const float* __restrict__ Gh,  const float* __restrict__ bgh,
                const float* __restrict__ Fw,  const float* __restrict__ bf,
                float* __restrict__ out)
{
  __shared__ __align__(16) float sHid[TBC][RC][COUTn];     // 24 KB  hid0 / gated hid chunk
  __shared__ float sP1[RC][4][COUTn];                      // 12 KB  gate partials (sig half)
  __shared__ float sP2[RC][4][COUTn];                      // 12 KB  gate partials (tanh half)
  __shared__ float sX[TBC][Rn];                            // 3 KB   x sequences
  __shared__ float sXm[TBC][RC + KW][CTn];                 // 2.5 KB x_mark window
  __shared__ float sRed[256];                              // 1 KB   fc reduction

  const int t   = threadIdx.x;
  const int g   = blockIdx.x >> 6;       // 0..7
  const int bcT = blockIdx.x & 63;       // 0..63 -> 8 bc pairs each
  const int o   = t & 63;                // gate/fc output chan; conv's i
  const int q   = t >> 6;                // wave id 0..3

  // ---------------- per-thread weight registers ----------------
  float wd[KW], wmr[CTn][KW];
#pragma unroll
  for (int k = 0; k < KW; ++k) wd[k] = Wd[(g*COUTn + o)*KW + k];
#pragma unroll
  for (int tt = 0; tt < CTn; ++tt)
#pragma unroll
    for (int k = 0; k < KW; ++k) wmr[tt][k] = Wm[((g*COUTn + o)*CTn + tt)*KW + k];
  const float cbias = bd[g*COUTn + o] + bm[g*COUTn + o];

  const float gd1 = Gd[g*NO2 + o];
  const float gd2 = Gd[g*NO2 + 64 + o];
  float gm1[CTn], gm2[CTn];
#pragma unroll
  for (int tt = 0; tt < CTn; ++tt) {
    gm1[tt] = Gm[(g*NO2 + o)*CTn + tt];
    gm2[tt] = Gm[(g*NO2 + 64 + o)*CTn + tt];
  }
  const float bg1 = bgd[g*NO2+o]    + bgm[g*NO2+o]    + bgh[g*NO2+o];
  const float bg2 = bgd[g*NO2+64+o] + bgm[g*NO2+64+o] + bgh[g*NO2+64+o];

  // Gh i-slice in registers: thread (o,q) holds Gh[o][q*16 .. q*16+15] (both halves)
  float gh1[16], gh2[16];
#pragma unroll
  for (int j = 0; j < 16; ++j) {
    gh1[j] = Gh[(g*NO2 + o)*COUTn      + q*16 + j];
    gh2[j] = Gh[(g*NO2 + 64 + o)*COUTn + q*16 + j];
  }

  // ---------------- load x sequences ----------------
  for (int idx = t; idx < TBC*Rn; idx += 256) {
    int l = idx / Rn, r = idx - l*Rn;
    int bc = bcT*TBC + l;
    int b = bc >> 6, c = bc & 63;
    sX[l][r] = x[((b*Rn + r)*Cn + c)*CINn + g];
  }

  float acc[TBC];
#pragma unroll
  for (int l = 0; l < TBC; ++l) acc[l] = 0.f;

  for (int c0 = 0; c0 < NCHUNK; ++c0) {
    const int r0 = c0 * RC;
    __syncthreads();                       // prev-chunk gate done -> safe to refill sXm
    // ---- x_mark window: rows r0-8 .. r0+RC-1 ----
    for (int idx = t; idx < TBC*(RC+KW)*CTn; idx += 256) {
      int l   = idx / ((RC+KW)*CTn);
      int rem = idx - l*(RC+KW)*CTn;
      int w   = rem >> 2, tt = rem & 3;
      int r   = r0 - KW + w;
      int bc  = bcT*TBC + l;
      int b   = bc >> 6, c = bc & 63;
      sXm[l][w][tt] = (r >= 0) ? xm[(((b*Rn + r)*Cn + c)*CINn + g)*CTn + tt] : 0.f;
    }
    __syncthreads();

    // ---- conv: hid0[l][rr][i] (i = o lane) ----
#pragma unroll 2
    for (int jj = 0; jj < TBC*RC/4; ++jj) {     // 24 rows per thread-wave slot
      int p  = q + 4*jj;
      int l  = p / RC, rr = p - l*RC;
      int rg = r0 + rr;
      float s = cbias;
#pragma unroll
      for (int k = 0; k < KW; ++k) {
        int rx = rg - KW + k;
        float xv = (rx >= 0) ? sX[l][rx] : 0.f;
        s = fmaf(xv, wd[k], s);
#pragma unroll
        for (int tt = 0; tt < CTn; ++tt)
          s = fmaf(sXm[l][rr+k][tt], wmr[tt][k], s);
      }
      sHid[l][rr][o] = s;
    }
    __syncthreads();

    // ---- gate, per l: partial dots (A) then combine+apply (B) ----
    for (int l = 0; l < TBC; ++l) {
#pragma unroll 2
      for (int rr = 0; rr < RC; ++rr) {
        const float4* hp = (const float4*)&sHid[l][rr][q*16];   // wave-uniform addr
        float4 h0 = hp[0], h1 = hp[1], h2 = hp[2], h3 = hp[3];
        float hv[16] = {h0.x,h0.y,h0.z,h0.w, h1.x,h1.y,h1.z,h1.w,
                        h2.x,h2.y,h2.z,h2.w, h3.x,h3.y,h3.z,h3.w};
        float p1 = 0.f, p2 = 0.f;
#pragma unroll
        for (int j = 0; j < 16; ++j) {
          p1 = fmaf(hv[j], gh1[j], p1);
          p2 = fmaf(hv[j], gh2[j], p2);
        }
        sP1[rr][q][o] = p1;
        sP2[rr][q][o] = p2;
      }
      __syncthreads();
#pragma unroll
      for (int rr3 = 0; rr3 < 3; ++rr3) {
        int rr = q*3 + rr3;
        int rg = r0 + rr;
        float xs = sX[l][rg];
        float g1 = fmaf(xs, gd1, bg1);
        float g2 = fmaf(xs, gd2, bg2);
#pragma unroll
        for (int tt = 0; tt < CTn; ++tt) {
          float v = sXm[l][rr+KW][tt];
          g1 = fmaf(v, gm1[tt], g1);
          g2 = fmaf(v, gm2[tt], g2);
        }
        g1 += sP1[rr][0][o] + sP1[rr][1][o] + sP1[rr][2][o] + sP1[rr][3][o];
        g2 += sP2[rr][0][o] + sP2[rr][1][o] + sP2[rr][2][o] + sP2[rr][3][o];
        float sig = 1.f / (1.f + __expf(-g1));
        float th  = 1.f - 2.f / (1.f + __expf(2.f*g2));
        float h0v = sHid[l][rr][o];
        sHid[l][rr][o] = fmaf(h0v, sig, (1.f - sig)*th);    // in-place gate
      }
      __syncthreads();
    }

    // ---- fc partial: acc[l] += sum_{i in my 16, rr} hid * Fw[g][o][i][r] ----
#pragma unroll 2
    for (int ii = 0; ii < 16; ++ii) {
      int i = q*16 + ii;
      const float4* fp = (const float4*)(Fw + (((g*COUTn + o)*COUTn + i)*Rn + r0));
      float4 f0 = fp[0], f1 = fp[1], f2 = fp[2];
      float wv[RC] = {f0.x,f0.y,f0.z,f0.w, f1.x,f1.y,f1.z,f1.w, f2.x,f2.y,f2.z,f2.w};
#pragma unroll
      for (int rr = 0; rr < RC; ++rr) {
#pragma unroll
        for (int l = 0; l < TBC; ++l)
          acc[l] = fmaf(sHid[l][rr][i], wv[rr], acc[l]);    // broadcast LDS read
      }
    }
  }

  // ---------------- cross-wave reduce + write ----------------
  const float bfv = bf[g*COUTn + o];
#pragma unroll
  for (int l = 0; l < TBC; ++l) {
    __syncthreads();
    sRed[t] = acc[l];
    __syncthreads();
    if (q == 0) {
      float s = sRed[o] + sRed[64+o] + sRed[128+o] + sRed[192+o];
      int bc = bcT*TBC + l;
      out[(bc*CINn + g)*COUTn + o] = s + bfv;
    }
  }
}

} // namespace

extern "C" void kernel_launch(void* const* d_in, const int* in_sizes, int n_in,
                              void* d_out, int out_size, void* d_ws, size_t ws_size,
                              hipStream_t stream) {
  const float* x   = (const float*)d_in[0];
  const float* xm  = (const float*)d_in[1];
  const float* Wd  = (const float*)d_in[2];
  const float* bd  = (const float*)d_in[3];
  const float* Wm  = (const float*)d_in[4];
  const float* bm  = (const float*)d_in[5];
  const float* Gd  = (const float*)d_in[6];
  const float* bgd = (const float*)d_in[7];
  const float* Gm  = (const float*)d_in[8];
  const float* bgm = (const float*)d_in[9];
  const float* Gh  = (const float*)d_in[10];
  const float* bgh = (const float*)d_in[11];
  const float* Fw  = (const float*)d_in[12];
  const float* bf  = (const float*)d_in[13];
  float* outp = (float*)d_out;

  fused_tb2d<<<dim3(512), dim3(256), 0, stream>>>(
      x, xm, Wd, bd, Wm, bm, Gd, bgd, Gm, bgm, Gh, bgh, Fw, bf, outp);
}

// Round 2
// 124.375 us; speedup vs baseline: 4.0897x; 4.0897x over previous
//
#include <hip/hip_runtime.h>
#include <hip/hip_bf16.h>
#include <math.h>

namespace {

typedef __attribute__((ext_vector_type(8))) short bh8;   // 8 bf16 (4 VGPR) MFMA A/B frag
typedef __attribute__((ext_vector_type(4))) float fx4;   // 4 f32 MFMA C/D frag

constexpr int Rn = 96, Cn = 64, CINn = 8, COUTn = 64, KW = 8, CTn = 4;
constexpr int TBC = 16;            // bc pairs per block
constexpr int RCH = 16;            // rows per chunk
constexpr int NCH = Rn / RCH;      // 6
constexpr int SH0 = 72;            // sHid0 row stride (bf16 elems): 144B, 16B-aligned, banks spread
constexpr int SXT = 32;            // sXtra row stride (64B)
constexpr int SFB = 1032;          // sHidF per-bc stride (2064B, 16B-aligned, banks spread)

__device__ inline ushort f2b(float f) {
  __hip_bfloat16 h = __float2bfloat16(f);
  return __builtin_bit_cast(ushort, h);
}
__device__ inline float b2f(ushort u) {
  return __builtin_bit_cast(float, (unsigned)u << 16);
}
__device__ inline bh8 pack8(const float* v) {
  bh8 r;
#pragma unroll
  for (int j = 0; j < 8; ++j) r[j] = (short)f2b(v[j]);
  return r;
}

#define MFMA16(a, b, c) __builtin_amdgcn_mfma_f32_16x16x32_bf16((a), (b), (c), 0, 0, 0)

__global__ __launch_bounds__(512, 2)
void fused_tb2d_v2(const float* __restrict__ x,  const float* __restrict__ xm,
                   const float* __restrict__ Wd, const float* __restrict__ bd,
                   const float* __restrict__ Wm, const float* __restrict__ bm,
                   const float* __restrict__ Gd, const float* __restrict__ bgd,
                   const float* __restrict__ Gm, const float* __restrict__ bgm,
                   const float* __restrict__ Gh, const float* __restrict__ bgh,
                   const float* __restrict__ Fw, const float* __restrict__ bf,
                   float* __restrict__ out)
{
  __shared__ __align__(16) ushort sHid0[256 * SH0];   // 36.9 KB  conv out (bf16), pos=bc*16+rr
  __shared__ __align__(16) ushort sXtra[256 * SXT];   // 16.0 KB  gate K-extension cols
  __shared__ __align__(16) ushort sHidF[TBC * SFB];   // 33.0 KB  gated hid, [bc][i][r] r-contig
  __shared__ __align__(16) float  sRed[8 * 256];      //  8.0 KB  fc cross-wave reduce

  const int t    = threadIdx.x;
  const int lane = t & 63;
  const int w    = t >> 6;          // wave 0..7
  const int il   = lane >> 4;       // 0..3
  const int mr   = lane & 15;
  const int s4   = w & 3;           // o-subtile
  const int hf   = w >> 2;          // 0/1: gate ntile half / fc i-half
  const int g    = blockIdx.x & 7;  // XCD-affine: blocks sharing Fw[g] land on one XCD L2
  const int bcT  = blockIdx.x >> 3; // 0..31

  // ---------------- conv weights in registers (channel ci = lane) ----------------
  const int ci = lane;
  float wdv[KW], wmv[CTn][KW];
#pragma unroll
  for (int k = 0; k < KW; ++k) wdv[k] = Wd[(g*COUTn + ci)*KW + k];
#pragma unroll
  for (int tt = 0; tt < CTn; ++tt)
#pragma unroll
    for (int k = 0; k < KW; ++k) wmv[tt][k] = Wm[((g*COUTn + ci)*CTn + tt)*KW + k];
  const float cbias = bd[g*COUTn + ci] + bm[g*COUTn + ci];

  // ---------------- gate A-frags (persistent registers) ----------------
  // gate^T: D[m=o2][n=pos], A[m=o2][k], k = 8*il + j. Wave w: sig rows s4*16.., tanh rows 64+s4*16..
  bh8 aS0, aS1, aT0, aT1, aSx, aTx;
  {
    float v[8];
    const float* p0 = Gh + ((size_t)(g*128) + s4*16 + mr)*64 + 8*il;
#pragma unroll
    for (int j = 0; j < 8; ++j) v[j] = p0[j];
    aS0 = pack8(v);
#pragma unroll
    for (int j = 0; j < 8; ++j) v[j] = p0[32 + j];
    aS1 = pack8(v);
    const float* p1 = p0 + 64*64;
#pragma unroll
    for (int j = 0; j < 8; ++j) v[j] = p1[j];
    aT0 = pack8(v);
#pragma unroll
    for (int j = 0; j < 8; ++j) v[j] = p1[32 + j];
    aT1 = pack8(v);

    float e[8] = {0.f,0.f,0.f,0.f,0.f,0.f,0.f,0.f};
    if (il == 0) {
      const int o2 = s4*16 + mr;
      e[0] = Gd[g*128 + o2];
#pragma unroll
      for (int tt = 0; tt < 4; ++tt) e[1+tt] = Gm[((size_t)(g*128) + o2)*4 + tt];
      e[5] = bgd[g*128 + o2] + bgm[g*128 + o2] + bgh[g*128 + o2];
    }
    aSx = pack8(e);
    float e2[8] = {0.f,0.f,0.f,0.f,0.f,0.f,0.f,0.f};
    if (il == 0) {
      const int o2 = 64 + s4*16 + mr;
      e2[0] = Gd[g*128 + o2];
#pragma unroll
      for (int tt = 0; tt < 4; ++tt) e2[1+tt] = Gm[((size_t)(g*128) + o2)*4 + tt];
      e2[5] = bgd[g*128 + o2] + bgm[g*128 + o2] + bgh[g*128 + o2];
    }
    aTx = pack8(e2);
  }

  // sXtra constant columns: col5 = 1.0 (bias lane), cols 6..31 = 0. Written once.
  if (t < 256) {
#pragma unroll
    for (int c5 = 5; c5 < SXT; ++c5)
      sXtra[t*SXT + c5] = (c5 == 5) ? (ushort)0x3F80 : (ushort)0;
  }

  fx4 facc = {0.f, 0.f, 0.f, 0.f};   // fc accumulator, wave (ot=s4, ih=hf), held all kernel

  for (int ch = 0; ch < NCH; ++ch) {
    const int r0 = ch * RCH;

    // ======== phase A: conv (VALU, reg sliding window) + xtra build ========
#pragma unroll 1
    for (int bci = 0; bci < 2; ++bci) {
      const int bcl = 2*w + bci;
      const int bcg = bcT*TBC + bcl;
      const int bb = bcg >> 6, cc_ = bcg & 63;
      const size_t xb = ((size_t)bb*Rn)*Cn*CINn + (size_t)cc_*CINn + g;  // + r*(Cn*CINn)
      float wx[8], wmx[8][4];
#pragma unroll
      for (int k = 0; k < 8; ++k) {          // rows r0-8..r0-1 -> slots k
        const int q = r0 - 8 + k;
        if (q >= 0) {
          const size_t xi = xb + (size_t)q*(Cn*CINn);
          wx[k] = x[xi];
          fx4 m4 = *(const fx4*)(xm + xi*4);
          wmx[k][0]=m4[0]; wmx[k][1]=m4[1]; wmx[k][2]=m4[2]; wmx[k][3]=m4[3];
        } else {
          wx[k]=0.f; wmx[k][0]=0.f; wmx[k][1]=0.f; wmx[k][2]=0.f; wmx[k][3]=0.f;
        }
      }
#pragma unroll
      for (int rr = 0; rr < RCH; ++rr) {
        float a = cbias;
#pragma unroll
        for (int k = 0; k < 8; ++k) {        // row r-8+k lives in slot (rr+k)&7
          const int sl = (rr + k) & 7;
          a = fmaf(wx[sl], wdv[k], a);
#pragma unroll
          for (int tt = 0; tt < 4; ++tt)
            a = fmaf(wmx[sl][tt], wmv[tt][k], a);
        }
        sHid0[(bcl*RCH + rr)*SH0 + ci] = f2b(a);
        if (rr < RCH - 1) {                  // slide: load row r0+rr into slot rr&7
          const size_t xi = xb + (size_t)(r0 + rr)*(Cn*CINn);
          const int sl = rr & 7;
          wx[sl] = x[xi];
          fx4 m4 = *(const fx4*)(xm + xi*4);
          wmx[sl][0]=m4[0]; wmx[sl][1]=m4[1]; wmx[sl][2]=m4[2]; wmx[sl][3]=m4[3];
        }
      }
    }
    if (t < 256) {                           // xtra cols 0..4: [xs, xm0..3]
      const int bcl = t >> 4, rr = t & 15;
      const int bcg = bcT*TBC + bcl;
      const int bb = bcg >> 6, cc_ = bcg & 63;
      const size_t xi = (((size_t)bb*Rn + (r0 + rr))*Cn + cc_)*CINn + g;
      const float xs = x[xi];
      fx4 m4 = *(const fx4*)(xm + xi*4);
      sXtra[t*SXT + 0] = f2b(xs);
      sXtra[t*SXT + 1] = f2b(m4[0]);
      sXtra[t*SXT + 2] = f2b(m4[1]);
      sXtra[t*SXT + 3] = f2b(m4[2]);
      sXtra[t*SXT + 4] = f2b(m4[3]);
    }
    __syncthreads();   // B1: sHid0/sXtra ready

    // ======== phase B: gate MFMA (K=64 hid + 32 extra) + sig/tanh epilogue ========
#pragma unroll 2
    for (int n_ = 0; n_ < 8; ++n_) {
      const int nt  = hf*8 + n_;             // ntile == bc
      const int pos = nt*16 + mr;
      const bh8 b0 = *(const bh8*)&sHid0[pos*SH0 + 8*il];
      const bh8 b1 = *(const bh8*)&sHid0[pos*SH0 + 32 + 8*il];
      const bh8 bx = *(const bh8*)&sXtra[pos*SXT + 8*il];
      fx4 accS = {0.f,0.f,0.f,0.f}, accT = {0.f,0.f,0.f,0.f};
      accS = MFMA16(aS0, b0, accS);
      accS = MFMA16(aS1, b1, accS);
      accS = MFMA16(aSx, bx, accS);
      accT = MFMA16(aT0, b0, accT);
      accT = MFMA16(aT1, b1, accT);
      accT = MFMA16(aTx, bx, accT);
      // D: col = mr = rr (pos-local), row = 4*il + cc = o-local; sig/tanh pair lane-local
#pragma unroll
      for (int cc = 0; cc < 4; ++cc) {
        const int o = s4*16 + 4*il + cc;
        const float g1 = accS[cc], g2 = accT[cc];
        const float sig = 1.f / (1.f + __expf(-g1));
        const float th  = 1.f - 2.f / (1.f + __expf(2.f*g2));
        const float h0  = b2f(sHid0[(nt*16 + mr)*SH0 + o]);
        const float h   = fmaf(h0, sig, (1.f - sig)*th);
        sHidF[nt*SFB + o*16 + mr] = f2b(h);   // [bc][i][r] layout, r = mr
      }
    }
    __syncthreads();   // B2: sHidF ready; sHid0/sXtra free for next chunk

    // ======== phase C: fc MFMA, out^T[o][bc] += Fw . hid ========
    {
      // A lane: o = s4*16+mr, i = hf*32 + ig*4 + il, r = r0 + rg*8 + j (r-contiguous 32B)
      const float* fb = Fw + (((size_t)(g*COUTn + s4*16 + mr))*COUTn + hf*32 + il)*Rn + r0;
      float stg[2][8];
      {
        fx4 u0 = *(const fx4*)(fb); fx4 u1 = *(const fx4*)(fb + 4);
        stg[0][0]=u0[0]; stg[0][1]=u0[1]; stg[0][2]=u0[2]; stg[0][3]=u0[3];
        stg[0][4]=u1[0]; stg[0][5]=u1[1]; stg[0][6]=u1[2]; stg[0][7]=u1[3];
      }
#pragma unroll
      for (int st = 0; st < 16; ++st) {
        const int ig = st >> 1, rg = st & 1;
        if (st < 15) {                        // 2-deep pipeline on the global A loads
          const int ign = (st + 1) >> 1, rgn = (st + 1) & 1;
          const float* p = fb + ign*(4*Rn) + rgn*8;
          fx4 u0 = *(const fx4*)(p); fx4 u1 = *(const fx4*)(p + 4);
          float* d = stg[(st + 1) & 1];
          d[0]=u0[0]; d[1]=u0[1]; d[2]=u0[2]; d[3]=u0[3];
          d[4]=u1[0]; d[5]=u1[1]; d[6]=u1[2]; d[7]=u1[3];
        }
        const bh8 aF = pack8(stg[st & 1]);
        const bh8 bF = *(const bh8*)&sHidF[mr*SFB + (hf*32 + ig*4 + il)*16 + rg*8];
        facc = MFMA16(aF, bF, facc);
      }
    }
    // no barrier: next-chunk conv writes sHid0 (disjoint from sHidF); B1 protects sHidF
  }

  // ---------------- fc reduce across i-halves + write ----------------
#pragma unroll
  for (int cc = 0; cc < 4; ++cc)
    sRed[w*256 + (4*il + cc)*16 + mr] = facc[cc];   // [wave][o_loc*16 + bc]
  __syncthreads();
#pragma unroll
  for (int e0 = 0; e0 < 2; ++e0) {
    const int e = t + e0*512;
    const int bcl = e >> 6, o = e & 63;
    const float v = sRed[(o >> 4)*256 + (o & 15)*16 + bcl]
                  + sRed[((o >> 4) + 4)*256 + (o & 15)*16 + bcl]
                  + bf[g*COUTn + o];
    out[((size_t)(bcT*TBC + bcl)*CINn + g)*COUTn + o] = v;
  }
}

} // namespace

extern "C" void kernel_launch(void* const* d_in, const int* in_sizes, int n_in,
                              void* d_out, int out_size, void* d_ws, size_t ws_size,
                              hipStream_t stream) {
  const float* x   = (const float*)d_in[0];
  const float* xm  = (const float*)d_in[1];
  const float* Wd  = (const float*)d_in[2];
  const float* bd  = (const float*)d_in[3];
  const float* Wm  = (const float*)d_in[4];
  const float* bm  = (const float*)d_in[5];
  const float* Gd  = (const float*)d_in[6];
  const float* bgd = (const float*)d_in[7];
  const float* Gm  = (const float*)d_in[8];
  const float* bgm = (const float*)d_in[9];
  const float* Gh  = (const float*)d_in[10];
  const float* bgh = (const float*)d_in[11];
  const float* Fw  = (const float*)d_in[12];
  const float* bf  = (const float*)d_in[13];
  float* outp = (float*)d_out;

  fused_tb2d_v2<<<dim3(256), dim3(512), 0, stream>>>(
      x, xm, Wd, bd, Wm, bm, Gd, bgd, Gm, bgm, Gh, bgh, Fw, bf, outp);
}

// Round 3
// 121.009 us; speedup vs baseline: 4.2034x; 1.0278x over previous
//
#include <hip/hip_runtime.h>
#include <hip/hip_bf16.h>

namespace {

typedef __attribute__((ext_vector_type(8))) short bh8;   // 8 bf16 = 4 VGPR MFMA frag
typedef __attribute__((ext_vector_type(4))) short sh4;   // 4 bf16
typedef __attribute__((ext_vector_type(4))) float fx4;

constexpr int Rn = 96, Cn = 64, CINn = 8, COUTn = 64;
constexpr int TBC = 8;            // bc pairs per block
constexpr int RCH = 16;           // rows per chunk
constexpr int NCH = Rn / RCH;     // 6
constexpr int XS  = 72;           // Xwin / sH0 row stride (ushorts): 144B, 16B-aligned, 2-way banks
constexpr int SFB = 1032;         // sHF per-bc stride (ushorts)
constexpr int NPOS = 393216;      // B*R*C*CIN
constexpr int NF4  = 786432;      // Fw elems / 4

__device__ inline ushort f2b(float f) {
  __hip_bfloat16 h = __float2bfloat16(f);
  return __builtin_bit_cast(ushort, h);
}
__device__ inline float b2f(ushort u) {
  return __builtin_bit_cast(float, (unsigned)u << 16);
}
__device__ inline bh8 pack8(const float* v) {
  bh8 r;
#pragma unroll
  for (int j = 0; j < 8; ++j) r[j] = (short)f2b(v[j]);
  return r;
}

#define MFMA16(a, b, c) __builtin_amdgcn_mfma_f32_16x16x32_bf16((a), (b), (c), 0, 0, 0)

// ---------------- pre-pass: feat8 pack + Fw -> bf16 ----------------
__global__ __launch_bounds__(256)
void cvt_k(const float* __restrict__ x, const float* __restrict__ xm,
           const float* __restrict__ Fw, ushort* __restrict__ feat,
           ushort* __restrict__ Fwb)
{
  const int bid = blockIdx.x, t = threadIdx.x;
  if (bid < NPOS / 256) {
    const int pos = bid * 256 + t;
    const float xs = x[pos];
    const fx4 m = *(const fx4*)(xm + (size_t)pos * 4);
    bh8 o;
    o[0] = (short)f2b(xs);
    o[1] = (short)f2b(m[0]); o[2] = (short)f2b(m[1]);
    o[3] = (short)f2b(m[2]); o[4] = (short)f2b(m[3]);
    o[5] = (short)0x3F80;    // constant 1.0 (bias lane)
    o[6] = 0; o[7] = 0;
    *(bh8*)(feat + (size_t)pos * 8) = o;
  } else {
    int j = (bid - NPOS / 256) * 256 + t;
#pragma unroll
    for (int it = 0; it < 6; ++it, j += 512 * 256) {
      const fx4 v = *(const fx4*)(Fw + (size_t)j * 4);
      sh4 o;
      o[0] = (short)f2b(v[0]); o[1] = (short)f2b(v[1]);
      o[2] = (short)f2b(v[2]); o[3] = (short)f2b(v[3]);
      *(sh4*)(Fwb + (size_t)j * 4) = o;
    }
  }
}

// ---------------- main fused kernel ----------------
__global__ __launch_bounds__(512, 4)
void fused_v3(const float* __restrict__ Wd, const float* __restrict__ bd,
              const float* __restrict__ Wm, const float* __restrict__ bm,
              const float* __restrict__ Gd, const float* __restrict__ bgd,
              const float* __restrict__ Gm, const float* __restrict__ bgm,
              const float* __restrict__ Gh, const float* __restrict__ bgh,
              const float* __restrict__ bf,
              const ushort* __restrict__ feat, const ushort* __restrict__ Fwb,
              float* __restrict__ out)
{
  __shared__ __align__(16) ushort sXw[128 * XS];      // 18.4 KB im2col [pos][tap*8+t]
  __shared__ __align__(16) ushort sH0[128 * XS];      // 18.4 KB conv out [pos][co]
  __shared__ __align__(16) ushort sXt[129 * 8];       //  2.1 KB feat8 per pos + zero row
  __shared__ __align__(16) ushort sHF[TBC * SFB];     // 16.5 KB gated hid [bc][i][r]
  __shared__ float sRed[8 * 128];                     //  4.0 KB fc cross-wave reduce

  const int t    = threadIdx.x;
  const int lane = t & 63;
  const int w    = t >> 6;
  const int il   = lane >> 4;
  const int mr   = lane & 15;
  const int s4   = w & 3;
  const int hf   = w >> 2;
  const int g    = blockIdx.x & 7;    // XCD-affine: Fwb[g]/feat-g stay in one XCD L2
  const int bcT  = blockIdx.x >> 3;

  // ---- conv A-frags: A[co][kdim], kdim = tap*8 + tslot; bias folded at (tap0, t=5) ----
  const int co = s4 * 16 + mr;
  const float cb = bd[g * 64 + co] + bm[g * 64 + co];
  bh8 aC0, aC1;
  {
    float v[8];
    v[0] = Wd[(g * 64 + co) * 8 + il];
#pragma unroll
    for (int t4 = 0; t4 < 4; ++t4) v[1 + t4] = Wm[((g * 64 + co) * 4 + t4) * 8 + il];
    v[5] = (il == 0) ? cb : 0.f; v[6] = 0.f; v[7] = 0.f;
    aC0 = pack8(v);
    v[0] = Wd[(g * 64 + co) * 8 + 4 + il];
#pragma unroll
    for (int t4 = 0; t4 < 4; ++t4) v[1 + t4] = Wm[((g * 64 + co) * 4 + t4) * 8 + 4 + il];
    v[5] = 0.f;
    aC1 = pack8(v);
  }

  // ---- gate A-frags (K = 64 hid + 8 feat-ext) ----
  bh8 aS0, aS1, aT0, aT1, aSx, aTx;
  {
    float v[8];
    const float* p0 = Gh + ((size_t)(g * 128) + s4 * 16 + mr) * 64 + 8 * il;
#pragma unroll
    for (int j = 0; j < 8; ++j) v[j] = p0[j];
    aS0 = pack8(v);
#pragma unroll
    for (int j = 0; j < 8; ++j) v[j] = p0[32 + j];
    aS1 = pack8(v);
    const float* p1 = p0 + 64 * 64;
#pragma unroll
    for (int j = 0; j < 8; ++j) v[j] = p1[j];
    aT0 = pack8(v);
#pragma unroll
    for (int j = 0; j < 8; ++j) v[j] = p1[32 + j];
    aT1 = pack8(v);

    float e[8] = {0.f,0.f,0.f,0.f,0.f,0.f,0.f,0.f};
    if (il == 0) {
      const int o2 = s4 * 16 + mr;
      e[0] = Gd[g * 128 + o2];
#pragma unroll
      for (int t4 = 0; t4 < 4; ++t4) e[1 + t4] = Gm[((size_t)(g * 128) + o2) * 4 + t4];
      e[5] = bgd[g * 128 + o2] + bgm[g * 128 + o2] + bgh[g * 128 + o2];
    }
    aSx = pack8(e);
    float e2[8] = {0.f,0.f,0.f,0.f,0.f,0.f,0.f,0.f};
    if (il == 0) {
      const int o2 = 64 + s4 * 16 + mr;
      e2[0] = Gd[g * 128 + o2];
#pragma unroll
      for (int t4 = 0; t4 < 4; ++t4) e2[1 + t4] = Gm[((size_t)(g * 128) + o2) * 4 + t4];
      e2[5] = bgd[g * 128 + o2] + bgm[g * 128 + o2] + bgh[g * 128 + o2];
    }
    aTx = pack8(e2);
  }

  if (t < 8) sXt[128 * 8 + t] = 0;    // shared zero row (NaN-safe bx for il>0)

  fx4 facc = {0.f, 0.f, 0.f, 0.f};

  for (int ch = 0; ch < NCH; ++ch) {
    const int r0 = ch * RCH;

    // ======== im2col: feat[q] -> Xwin rows q+1..q+8 (tap k = q-r+8) ========
    if (t < 192) {
      const int bcl = t / 24;
      const int d   = (t - bcl * 24) - 8;    // q = r0 + d, d in [-8, 15]
      const int q   = r0 + d;
      bh8 f;
      if (q >= 0) {
        const int bcg = bcT * 8 + bcl, b = bcg >> 6, c = bcg & 63;
        f = *(const bh8*)(feat + (size_t)(((b * Rn + q) * Cn + c) * CINn + g) * 8);
      } else {
        bh8 z = {0, 0, 0, 0, 0, (short)0x3F80, 0, 0};   // bias lane survives padding
        f = z;
      }
#pragma unroll
      for (int k = 0; k < 8; ++k) {
        const int rr = d + 8 - k;
        if (rr >= 0 && rr < RCH)
          *(bh8*)&sXw[(bcl * RCH + rr) * XS + k * 8] = f;
      }
      if (d >= 0 && d < RCH)
        *(bh8*)&sXt[(bcl * RCH + d) * 8] = f;
    }
    __syncthreads();   // B1

    // ======== conv MFMA: hid0[pos][co] ========
#pragma unroll
    for (int jj = 0; jj < 4; ++jj) {
      const int pos = (hf * 4 + jj) * 16 + mr;
      const bh8 b0 = *(const bh8*)&sXw[pos * XS + 8 * il];
      const bh8 b1 = *(const bh8*)&sXw[pos * XS + 32 + 8 * il];
      fx4 a = {0.f, 0.f, 0.f, 0.f};
      a = MFMA16(aC0, b0, a);
      a = MFMA16(aC1, b1, a);
      sh4 o4;
#pragma unroll
      for (int cc = 0; cc < 4; ++cc) o4[cc] = (short)f2b(a[cc]);
      *(sh4*)&sH0[pos * XS + s4 * 16 + 4 * il] = o4;    // rows 4il+cc contiguous
    }
    __syncthreads();   // B2

    // ======== gate MFMA + sig/tanh ========
#pragma unroll
    for (int jj = 0; jj < 4; ++jj) {
      const int nt = hf * 4 + jj;
      const int pos = nt * 16 + mr;
      const bh8 b0 = *(const bh8*)&sH0[pos * XS + 8 * il];
      const bh8 b1 = *(const bh8*)&sH0[pos * XS + 32 + 8 * il];
      const ushort* xp = (il == 0) ? &sXt[pos * 8] : &sXt[128 * 8];
      const bh8 bx = *(const bh8*)xp;
      fx4 accS = {0.f,0.f,0.f,0.f}, accT = {0.f,0.f,0.f,0.f};
      accS = MFMA16(aS0, b0, accS);
      accS = MFMA16(aS1, b1, accS);
      accS = MFMA16(aSx, bx, accS);
      accT = MFMA16(aT0, b0, accT);
      accT = MFMA16(aT1, b1, accT);
      accT = MFMA16(aTx, bx, accT);
      const sh4 h4 = *(const sh4*)&sH0[pos * XS + s4 * 16 + 4 * il];
#pragma unroll
      for (int cc = 0; cc < 4; ++cc) {
        const float g1 = accS[cc], g2 = accT[cc];
        const float sig = 1.f / (1.f + __expf(-g1));
        const float th  = 1.f - 2.f / (1.f + __expf(2.f * g2));
        const float h   = fmaf(b2f((ushort)h4[cc]), sig, (1.f - sig) * th);
        sHF[nt * SFB + (s4 * 16 + 4 * il + cc) * 16 + mr] = f2b(h);
      }
    }
    __syncthreads();   // B3

    // ======== fc MFMA: facc[o-local][bc] += Fwb . hid ========
    {
      const ushort* fb = Fwb + ((size_t)(g * 64 + s4 * 16 + mr) * 64 + hf * 32 + il) * 96 + r0;
#pragma unroll
      for (int st = 0; st < 16; ++st) {
        const int ig = st >> 1, rg = st & 1;
        const bh8 aF = *(const bh8*)(fb + ig * 4 * 96 + rg * 8);
        const bh8 bF = *(const bh8*)&sHF[(mr & 7) * SFB + (hf * 32 + ig * 4 + il) * 16 + rg * 8];
        facc = MFMA16(aF, bF, facc);
      }
    }
    // no barrier: next im2col writes sXw/sXt (disjoint from sHF); B1/B2 fence reuse
  }

  // ---- reduce i-halves + write ----
  if (mr < 8) {
#pragma unroll
    for (int cc = 0; cc < 4; ++cc)
      sRed[(hf * 4 + s4) * 128 + (4 * il + cc) * 8 + mr] = facc[cc];
  }
  __syncthreads();
  {
    const int bcl = t >> 6, o = t & 63;
    const int s4r = o >> 4, oc = o & 15;
    const float v = sRed[s4r * 128 + oc * 8 + bcl]
                  + sRed[(4 + s4r) * 128 + oc * 8 + bcl]
                  + bf[g * 64 + o];
    out[((size_t)(bcT * 8 + bcl) * CINn + g) * 64 + o] = v;
  }
}

} // namespace

extern "C" void kernel_launch(void* const* d_in, const int* in_sizes, int n_in,
                              void* d_out, int out_size, void* d_ws, size_t ws_size,
                              hipStream_t stream) {
  const float* x   = (const float*)d_in[0];
  const float* xm  = (const float*)d_in[1];
  const float* Wd  = (const float*)d_in[2];
  const float* bd  = (const float*)d_in[3];
  const float* Wm  = (const float*)d_in[4];
  const float* bm  = (const float*)d_in[5];
  const float* Gd  = (const float*)d_in[6];
  const float* bgd = (const float*)d_in[7];
  const float* Gm  = (const float*)d_in[8];
  const float* bgm = (const float*)d_in[9];
  const float* Gh  = (const float*)d_in[10];
  const float* bgh = (const float*)d_in[11];
  const float* Fw  = (const float*)d_in[12];
  const float* bf  = (const float*)d_in[13];
  float* outp = (float*)d_out;

  ushort* feat = (ushort*)d_ws;                                   // 6.29 MB
  ushort* Fwb  = (ushort*)((char*)d_ws + (size_t)NPOS * 16);      // 6.29 MB

  cvt_k<<<dim3(NPOS / 256 + 512), dim3(256), 0, stream>>>(x, xm, Fw, feat, Fwb);
  fused_v3<<<dim3(512), dim3(512), 0, stream>>>(
      Wd, bd, Wm, bm, Gd, bgd, Gm, bgm, Gh, bgh, bf, feat, Fwb, outp);
}